// Round 7
// baseline (30.999 us; speedup 1.0000x reference)
//
#include <hip/hip_runtime.h>

// Output layout (flat float32, reference return order):
//   out0: voxel_features  [N, 4]
//   out1: voxel_coords    [N, 4]   (int values written as float)
//   out2: patch_center_xyz[V, 3]
//   out3: patch_num_list  [B]      (int values written as float)
//
// SINGLE persistent dispatch: 2048 blocks (8/CU x 256 CU, fully co-resident).
// Each block: issue first 64-voxel tile-pair loads -> in-block scan of patch
// counts (hidden under the loads) -> coords range-scatter for its own patch
// (no search) -> reduce pair 0 -> load+reduce pair 1.

#define P_MAX 4096   // LDS guard for in-block scan (P = 2048 in practice)

__device__ __forceinline__ void mean_reduce_store(
    const float4& a0, const float4& a1, const float4& a2, const float4& a3,
    int np, int t, int voxel, float4* __restrict__ out0)
{
    float sx = a0.x + a1.x + a2.x + a3.x;
    float sy = a0.y + a1.y + a2.y + a3.y;
    float sz = a0.z + a1.z + a2.z + a3.z;
    float sw = a0.w + a1.w + a2.w + a3.w;
#pragma unroll
    for (int m = 4; m; m >>= 1) {           // xor 4,2,1: stays in 8-lane group
        sx += __shfl_xor(sx, m);
        sy += __shfl_xor(sy, m);
        sz += __shfl_xor(sz, m);
        sw += __shfl_xor(sw, m);
    }
    if (t == 0) {
        float inv = 1.0f / fmaxf((float)np, 1.0f);
        out0[voxel] = make_float4(sx * inv, sy * inv, sz * inv, sw * inv);
    }
}

__global__ __launch_bounds__(256) void fused_persistent_kernel(
    const float4* __restrict__ pv,     // [N*32] float4  (N,32,4)
    const int*    __restrict__ npts,   // [N]
    const int4*   __restrict__ coords, // [N]
    const int*    __restrict__ counts, // [P]
    const float*  __restrict__ centers,// [V,2]
    const int*    __restrict__ nums,   // [B]
    float4* __restrict__ out0,         // [N] features
    float4* __restrict__ out1,         // [N] coords-as-float
    float*  __restrict__ out2,         // [V,3]
    float*  __restrict__ out3,         // [B]
    int n_voxels, int P, int V, int B,
    int vpb, int ppb)                  // voxels per block, patches per block
{
    __shared__ int s_accu[P_MAX];
    __shared__ int s_wsum[4];

    const int b   = blockIdx.x;
    const int tid = threadIdx.x;
    const int t   = tid & 7;           // lane within 8-lane voxel group
    const int g   = tid >> 3;          // voxel group 0..31

    const int vbase = b * vpb;

    // ---- tile pair 0: issue 8 independent float4 loads per lane ----
    int vA = vbase + g;
    int vB = vbase + 32 + g;
    bool okA = vA < n_voxels, okB = vB < n_voxels;
    float4 a0, a1, a2, a3, c0, c1, c2, c3;
    int npA = 0, npB = 0;
    if (okA) {
        const float4* base = pv + (size_t)vA * 32;
        a0 = base[t]; a1 = base[t + 8]; a2 = base[t + 16]; a3 = base[t + 24];
        if (t == 0) npA = npts[vA];
    }
    if (okB) {
        const float4* base = pv + (size_t)vB * 32;
        c0 = base[t]; c1 = base[t + 8]; c2 = base[t + 16]; c3 = base[t + 24];
        if (t == 0) npB = npts[vB];
    }

    // ---- in-block scan of counts (hidden under the in-flight loads) ----
    {
        const int chunk = (P + 255) >> 8;
        const int cbeg = tid * chunk;
        const int cend = min(cbeg + chunk, P);
        int s = 0;
        for (int i = cbeg; i < cend; ++i) s += counts[i];
        const int lane = tid & 63;
        const int wave = tid >> 6;
        int acc = s;
#pragma unroll
        for (int off = 1; off < 64; off <<= 1) {
            int u = __shfl_up(acc, off);
            if (lane >= off) acc += u;
        }
        if (lane == 63) s_wsum[wave] = acc;
        __syncthreads();
        int wpre = 0;
        for (int w = 0; w < wave; ++w) wpre += s_wsum[w];
        int run = wpre + acc - s;
        for (int i = cbeg; i < cend; ++i) {
            run += counts[i];                  // L1-hot re-read
            s_accu[i] = run;
        }
        __syncthreads();
    }

    // ---- coords range-scatter for this block's patch range ----
    const int pBeg = b * ppb;
    if (pBeg < P) {
        const int pEnd = min(pBeg + ppb, P);
        const int sBeg = (pBeg == 0) ? 0 : s_accu[pBeg - 1];
        const int sEnd = s_accu[pEnd - 1];
        for (int j = sBeg + tid; j < sEnd; j += 256) {
            int p = pBeg;
            while (p < pEnd - 1 && s_accu[p] <= j) ++p;
            int4 c = coords[j];
            out1[j] = make_float4((float)p, (float)c.y, (float)c.z, (float)c.w);
        }
    }
    if (b == 0) {
        for (int i = tid; i < V; i += 256) {
            out2[3 * i + 0] = centers[2 * i + 0];
            out2[3 * i + 1] = centers[2 * i + 1];
            out2[3 * i + 2] = 0.0f;
        }
        for (int i = tid; i < B; i += 256) out3[i] = (float)nums[i];
    }

    // ---- reduce tile pair 0 ----
    if (okA) mean_reduce_store(a0, a1, a2, a3, npA, t, vA, out0);
    if (okB) mean_reduce_store(c0, c1, c2, c3, npB, t, vB, out0);

    // ---- tile pair 1 ----
    vA = vbase + 64 + g;
    vB = vbase + 96 + g;
    okA = vA < n_voxels; okB = vB < n_voxels;
    if (okA) {
        const float4* base = pv + (size_t)vA * 32;
        a0 = base[t]; a1 = base[t + 8]; a2 = base[t + 16]; a3 = base[t + 24];
        if (t == 0) npA = npts[vA];
    }
    if (okB) {
        const float4* base = pv + (size_t)vB * 32;
        c0 = base[t]; c1 = base[t + 8]; c2 = base[t + 16]; c3 = base[t + 24];
        if (t == 0) npB = npts[vB];
    }
    if (okA) mean_reduce_store(a0, a1, a2, a3, npA, t, vA, out0);
    if (okB) mean_reduce_store(c0, c1, c2, c3, npB, t, vB, out0);
}

extern "C" void kernel_launch(void* const* d_in, const int* in_sizes, int n_in,
                              void* d_out, int out_size, void* d_ws, size_t ws_size,
                              hipStream_t stream) {
    const float* pv      = (const float*)d_in[0];  // [N,32,4]
    const int*   npts    = (const int*)d_in[1];    // [N]
    const int*   coords  = (const int*)d_in[2];    // [N,4]
    const int*   pcounts = (const int*)d_in[3];    // [P]
    const float* centers = (const float*)d_in[4];  // [V,2]
    const int*   vnums   = (const int*)d_in[5];    // [B]

    const int N = in_sizes[1];       // 262144 voxels
    const int P = in_sizes[3];       // 2048 patches
    const int V = in_sizes[4] / 2;   // 2048 centers
    const int B = in_sizes[5];       // 4

    float* out0 = (float*)d_out;
    float* out1 = out0 + (size_t)N * 4;
    float* out2 = out1 + (size_t)N * 4;
    float* out3 = out2 + (size_t)V * 3;

    const int vpb    = 128;                          // 4 tiles of 32 voxels
    const int blocks = (N + vpb - 1) / vpb;          // 2048 = 8/CU x 256 CU
    const int ppb    = (P + blocks - 1) / blocks;    // 1

    fused_persistent_kernel<<<blocks, 256, 0, stream>>>(
        (const float4*)pv, npts, (const int4*)coords, pcounts, centers, vnums,
        (float4*)out0, (float4*)out1, out2, out3,
        N, P, V, B, vpb, ppb);
}

// Round 8
// 26.246 us; speedup vs baseline: 1.1811x; 1.1811x over previous
//
#include <hip/hip_runtime.h>

// Output layout (flat float32, reference return order):
//   out0: voxel_features  [N, 4]
//   out1: voxel_coords    [N, 4]   (int values written as float)
//   out2: patch_center_xyz[V, 3]
//   out3: patch_num_list  [B]      (int values written as float)
//
// SINGLE dispatch, 2048 persistent blocks (8/CU), 128 voxels/block processed
// as 4 software-pipelined iterations (next iter's loads issued before current
// iter's reduce -> loads continuously in flight, no per-wave drain).
// Blocks 0..511 additionally scan the patch counts in-block and range-scatter
// coords for 4 patches each (hidden under their first in-flight loads).

#define P_MAX 4096   // LDS guard for in-block scan (P = 2048 in practice)

__device__ __forceinline__ void reduce_store(
    float4 a0, float4 a1, float4 a2, float4 a3,
    int np, int t, int voxel, float4* __restrict__ out0)
{
    float sx = a0.x + a1.x + a2.x + a3.x;
    float sy = a0.y + a1.y + a2.y + a3.y;
    float sz = a0.z + a1.z + a2.z + a3.z;
    float sw = a0.w + a1.w + a2.w + a3.w;
#pragma unroll
    for (int m = 4; m; m >>= 1) {            // xor 4,2,1: stays in 8-lane group
        sx += __shfl_xor(sx, m);
        sy += __shfl_xor(sy, m);
        sz += __shfl_xor(sz, m);
        sw += __shfl_xor(sw, m);
    }
    if (t == 0) {
        float inv = 1.0f / fmaxf((float)np, 1.0f);
        out0[voxel] = make_float4(sx * inv, sy * inv, sz * inv, sw * inv);
    }
}

__global__ __launch_bounds__(256) void fused_pipe_kernel(
    const float4* __restrict__ pv,     // [N*32] float4  (N,32,4)
    const int*    __restrict__ npts,   // [N]
    const int4*   __restrict__ coords, // [N]
    const int*    __restrict__ counts, // [P]
    const float*  __restrict__ centers,// [V,2]
    const int*    __restrict__ nums,   // [B]
    float4* __restrict__ out0,         // [N] features
    float4* __restrict__ out1,         // [N] coords-as-float
    float*  __restrict__ out2,         // [V,3]
    float*  __restrict__ out3,         // [B]
    int n_voxels, int P, int V, int B,
    int coordBlocks, int ppb)
{
    __shared__ int s_accu[P_MAX];
    __shared__ int s_wsum[4];

    const int b   = blockIdx.x;
    const int tid = threadIdx.x;
    const int t   = tid & 7;            // lane within 8-lane voxel group
    const int g   = tid >> 3;           // voxel group 0..31 within block-iter

    const int vbase = b * 128;

    // ---- iteration 0: issue loads immediately ----
    float4 a0, a1, a2, a3;
    int npA = 0;
    int v0i = vbase + g;
    bool ok0 = v0i < n_voxels;
    if (ok0) {
        const float4* base = pv + (size_t)v0i * 32;
        a0 = base[t]; a1 = base[t + 8]; a2 = base[t + 16]; a3 = base[t + 24];
        npA = npts[v0i];                // all 8 lanes load (broadcast), no mask
    }

    // ---- coords blocks: scan + scatter, hidden under in-flight loads ----
    if (b < coordBlocks) {
        {
            const int chunk = (P + 255) >> 8;
            const int cbeg = tid * chunk;
            const int cend = min(cbeg + chunk, P);
            int s = 0;
            for (int i = cbeg; i < cend; ++i) s += counts[i];
            const int lane = tid & 63;
            const int wave = tid >> 6;
            int acc = s;
#pragma unroll
            for (int off = 1; off < 64; off <<= 1) {
                int u = __shfl_up(acc, off);
                if (lane >= off) acc += u;
            }
            if (lane == 63) s_wsum[wave] = acc;
            __syncthreads();
            int wpre = 0;
            for (int w = 0; w < wave; ++w) wpre += s_wsum[w];
            int run = wpre + acc - s;
            for (int i = cbeg; i < cend; ++i) {
                run += counts[i];               // L1-hot re-read
                s_accu[i] = run;
            }
            __syncthreads();
        }
        const int pBeg = b * ppb;
        if (pBeg < P) {
            const int pEnd = min(pBeg + ppb, P);
            const int sBeg = (pBeg == 0) ? 0 : s_accu[pBeg - 1];
            const int sEnd = s_accu[pEnd - 1];
            for (int j = sBeg + tid; j < sEnd; j += 256) {
                int p = pBeg;
                while (p < pEnd - 1 && s_accu[p] <= j) ++p;
                int4 c = coords[j];
                out1[j] = make_float4((float)p, (float)c.y, (float)c.z, (float)c.w);
            }
        }
        if (b == 0) {
            for (int i = tid; i < V; i += 256) {
                out2[3 * i + 0] = centers[2 * i + 0];
                out2[3 * i + 1] = centers[2 * i + 1];
                out2[3 * i + 2] = 0.0f;
            }
            for (int i = tid; i < B; i += 256) out3[i] = (float)nums[i];
        }
    }

    // ---- software-pipelined mean loop: 4 iterations of 32 voxels ----
#pragma unroll
    for (int it = 0; it < 4; ++it) {
        float4 b0, b1, b2, b3;
        int npB = 0;
        int vNext = vbase + (it + 1) * 32 + g;
        bool okN = (it < 3) && (vNext < n_voxels);
        if (okN) {                       // issue next iter's loads FIRST
            const float4* base = pv + (size_t)vNext * 32;
            b0 = base[t]; b1 = base[t + 8]; b2 = base[t + 16]; b3 = base[t + 24];
            npB = npts[vNext];
        }
        int vCur = vbase + it * 32 + g;
        if (vCur < n_voxels) {
            reduce_store(a0, a1, a2, a3, npA, t, vCur, out0);
        }
        a0 = b0; a1 = b1; a2 = b2; a3 = b3;   // renamed away by unroll
        npA = npB;
    }
}

extern "C" void kernel_launch(void* const* d_in, const int* in_sizes, int n_in,
                              void* d_out, int out_size, void* d_ws, size_t ws_size,
                              hipStream_t stream) {
    const float* pv      = (const float*)d_in[0];  // [N,32,4]
    const int*   npts    = (const int*)d_in[1];    // [N]
    const int*   coords  = (const int*)d_in[2];    // [N,4]
    const int*   pcounts = (const int*)d_in[3];    // [P]
    const float* centers = (const float*)d_in[4];  // [V,2]
    const int*   vnums   = (const int*)d_in[5];    // [B]

    const int N = in_sizes[1];       // 262144 voxels
    const int P = in_sizes[3];       // 2048 patches
    const int V = in_sizes[4] / 2;   // 2048 centers
    const int B = in_sizes[5];       // 4

    float* out0 = (float*)d_out;
    float* out1 = out0 + (size_t)N * 4;
    float* out2 = out1 + (size_t)N * 4;
    float* out3 = out2 + (size_t)V * 3;

    const int blocks      = (N + 127) / 128;                 // 2048 = 8/CU
    const int coordBlocks = 512;
    const int ppb         = (P + coordBlocks - 1) / coordBlocks;  // 4

    fused_pipe_kernel<<<blocks, 256, 0, stream>>>(
        (const float4*)pv, npts, (const int4*)coords, pcounts, centers, vnums,
        (float4*)out0, (float4*)out1, out2, out3,
        N, P, V, B, coordBlocks, ppb);
}